// Round 20
// baseline (110.815 us; speedup 1.0000x reference)
//
#include <hip/hip_runtime.h>
#include <hip/hip_bf16.h>

#define NROW 8192
#define DDIM 512
#define MARGIN 0.2f

typedef __bf16 bf16x8 __attribute__((ext_vector_type(8)));
typedef float f32x4 __attribute__((ext_vector_type(4)));

__device__ __forceinline__ void gload16(const void* g, void* l) {
    __builtin_amdgcn_global_load_lds(
        (const __attribute__((address_space(1))) void*)g,
        (__attribute__((address_space(3))) void*)l, 16, 0, 0);
}

#define BAR() __builtin_amdgcn_s_barrier()

// ---------------------------------------------------------------------------
// prep: blocks 0..N-1 handle im (convert + idat={||im||^2, MARGIN+||im-s||}),
//       N..2N-1 handle ex (convert + ||ex||^2)
// ---------------------------------------------------------------------------
__global__ __launch_bounds__(256) void prep_kernel(
    const float* __restrict__ im, const float* __restrict__ s,
    const float* __restrict__ ex,
    ushort* __restrict__ Abf, ushort* __restrict__ Bbf,
    float2* __restrict__ idat, float* __restrict__ exsq) {
    int b = blockIdx.x;
    bool isim = b < NROW;
    int row = isim ? b : b - NROW;
    const float* src = isim ? im : ex;
    ushort* dst = isim ? Abf : Bbf;
    int tid = threadIdx.x;

    float2 v = ((const float2*)(src + (size_t)row * DDIM))[tid];
    __hip_bfloat16 hx = __float2bfloat16(v.x);
    __hip_bfloat16 hy = __float2bfloat16(v.y);
    unsigned packed = (unsigned)*(const ushort*)&hx | ((unsigned)*(const ushort*)&hy << 16);
    ((unsigned*)(dst + (size_t)row * DDIM))[tid] = packed;

    float ssq = v.x * v.x + v.y * v.y;
    float dsq = 0.f;
    if (isim) {
        float2 sv = ((const float2*)(s + (size_t)row * DDIM))[tid];
        float dx = v.x - sv.x, dy = v.y - sv.y;
        dsq = dx * dx + dy * dy;
    }
    #pragma unroll
    for (int off = 32; off > 0; off >>= 1) {
        ssq += __shfl_down(ssq, off);
        dsq += __shfl_down(dsq, off);
    }
    __shared__ float sred[8];
    int lane = tid & 63, w = tid >> 6;
    if (lane == 0) { sred[w] = ssq; sred[4 + w] = dsq; }
    __syncthreads();
    if (tid == 0) {
        float S = sred[0] + sred[1] + sred[2] + sred[3];
        float Dd = sred[4] + sred[5] + sred[6] + sred[7];
        if (isim) idat[row] = make_float2(S, MARGIN + sqrtf(Dd));
        else      exsq[row] = S;
    }
}

// ---------------------------------------------------------------------------
// 128x128 GEMM + fused epilogue. 4 waves (2x2), BK=32, dbuf LDS = 32.2 KB,
// 4 blocks/CU (R17: OccupancyPercent 40% -> mechanism engaged, gemm 120->107)
// SWIZZLE FIX vs R17: R17's chunk = g ^ (row&3) left lanes {l15,l15+4,+8,+12}
// on identical (row-parity, chunk) -> 4-way bank conflict (8.4M counted,
// 1.58x LDS-read cost per m136). New: chunk = g ^ (row&3) ^ ((row>>2)&3).
// Enumerating l15=0..15: each (parity,chunk) pair appears exactly 2x ->
// 2-way = free (m136). Staging side: per-thread source pre-swizzle
// lc = pc ^ (r&3) ^ ((r>>2)&3); rows r and r+64 share it (+64 preserves
// both (r&3) and ((r>>2)&3)); LDS dest stays linear (gload_lds-compliant).
// Ledger (R14/R17-validated): prologue STAGE(0,1), vmcnt(4) seals tile 0;
// iter t: 8 ds_read_b128 + 16 MFMA (compiler lgkm waits), BAR, STAGE(t+2),
// vmcnt(4) seals t+1 (t<14; vmcnt(0) at 14), sched_barrier(0), BAR.
// XCD map (R9-validated): XCD c owns bi in [8c,8c+8); 8x8 bj windows.
// ---------------------------------------------------------------------------
__global__ __launch_bounds__(256, 4) void gemm_cost_kernel(
    const ushort* __restrict__ Abf, const ushort* __restrict__ Bbf,
    const float2* __restrict__ idat, const float* __restrict__ exsq,
    float* __restrict__ partials) {
    __shared__ __align__(16) ushort sA[2][4096];  // 2 x 8 KB
    __shared__ __align__(16) ushort sB[2][4096];  // 2 x 8 KB
    __shared__ float redbuf[4];

    // XCD-aware window mapping (bijective over 64x64 tiles)
    int bid0 = blockIdx.x;
    int c = bid0 & 7;            // assumed XCD id
    int sq = bid0 >> 3;          // 0..511 within XCD
    int win = sq >> 6;           // 0..7  bj window
    int pos = sq & 63;           // 0..63 within 8x8 window
    int bi = c * 8 + (pos & 7);
    int bj = win * 8 + (pos >> 3);
    int bid = bi * 64 + bj;      // bijective, for partials
    int ibase = bi * 128, jbase = bj * 128;
    int tid = threadIdx.x, lane = tid & 63, w = tid >> 6;
    int wr = w >> 1, wc = w & 1;

    // staging per-thread constants: r covers rows r and r+64 (same swizzle)
    int r = tid >> 2;            // 0..63
    int pc = tid & 3;            // physical 16B chunk in 64B row
    int lc = pc ^ (r & 3) ^ ((r >> 2) & 3);   // double-XOR source pre-swizzle
    const ushort* aG = Abf + (size_t)(ibase + r) * DDIM + lc * 8;
    const ushort* bG = Bbf + (size_t)(jbase + r) * DDIM + lc * 8;
    ushort* aL = &sA[0][0] + r * 32 + pc * 8;
    ushort* bL = &sB[0][0] + r * 32 + pc * 8;

    auto STAGE = [&](int kt) {
        if (kt >= 16) return;
        const ushort* ga = aG + kt * 32;
        const ushort* gb = bG + kt * 32;
        ushort* la = aL + (kt & 1) * 4096;
        ushort* lb = bL + (kt & 1) * 4096;
        gload16(ga, la);
        gload16(ga + 64 * DDIM, la + 2048);
        gload16(gb, lb);
        gload16(gb + 64 * DDIM, lb + 2048);
    };

    // ds_read constants (read-side double-XOR: chunk ^= (row&3)^((row>>2)&3),
    // and for row = quad*16 + l15 those equal (l15&3) and ((l15>>2)&3))
    int l15 = lane & 15;
    int koffb = (((lane >> 4) ^ (l15 & 3) ^ ((l15 >> 2) & 3)) * 8);
    int aoff = (wr * 64 + l15) * 32;
    int boff = (wc * 64 + l15) * 32;

    f32x4 acc[4][4] = {};

    // prologue: tiles 0,1 staged (8 loads); vmcnt(4) seals tile 0
    STAGE(0); STAGE(1);
    asm volatile("s_waitcnt vmcnt(4)" ::: "memory");
    __builtin_amdgcn_sched_barrier(0);
    BAR();

    #pragma unroll
    for (int t = 0; t < 16; ++t) {
        const ushort* pA = &sA[t & 1][0];
        const ushort* pB = &sB[t & 1][0];
        bf16x8 a[4], b[4];

        #pragma unroll
        for (int m = 0; m < 4; ++m)
            a[m] = *(const bf16x8*)(pA + aoff + m * 512 + koffb);
        #pragma unroll
        for (int n = 0; n < 4; ++n)
            b[n] = *(const bf16x8*)(pB + boff + n * 512 + koffb);
        #pragma unroll
        for (int m = 0; m < 4; ++m)
            #pragma unroll
            for (int n = 0; n < 4; ++n)
                acc[m][n] = __builtin_amdgcn_mfma_f32_16x16x32_bf16(a[m], b[n], acc[m][n], 0, 0, 0);

        BAR();                        // this tile's reads consumed block-wide
        STAGE(t + 2);                 // overwrite buf[t&1] with tile t+2
        if (t < 14)       asm volatile("s_waitcnt vmcnt(4)" ::: "memory");
        else if (t == 14) asm volatile("s_waitcnt vmcnt(0)" ::: "memory");
        __builtin_amdgcn_sched_barrier(0);
        BAR();                        // block-wide seal of tile t+1
    }

    // epilogue: cost = max(idat.y - sqrt(max(idat.x + exsq[j] - 2*dot, 0)), 0)
    // C/D layout: col = lane&15, row = (lane>>4)*4 + reg
    float jt[4];
    #pragma unroll
    for (int n = 0; n < 4; ++n) jt[n] = exsq[jbase + wc * 64 + n * 16 + l15];
    int r0 = (lane >> 4) * 4;
    float lsum = 0.f;
    #pragma unroll
    for (int m = 0; m < 4; ++m) {
        #pragma unroll
        for (int rg = 0; rg < 4; ++rg) {
            int i = ibase + wr * 64 + m * 16 + r0 + rg;
            float2 id = idat[i];
            #pragma unroll
            for (int n = 0; n < 4; ++n) {
                float d2 = fmaxf(id.x + jt[n] - 2.0f * acc[m][n][rg], 0.0f);
                lsum += fmaxf(id.y - sqrtf(d2), 0.0f);
            }
        }
    }
    #pragma unroll
    for (int off = 32; off > 0; off >>= 1) lsum += __shfl_down(lsum, off);
    if (lane == 0) redbuf[w] = lsum;
    __syncthreads();
    if (tid == 0) partials[bid] = redbuf[0] + redbuf[1] + redbuf[2] + redbuf[3];
}

// ---------------------------------------------------------------------------
// deterministic final reduce: 4096 partials -> mean
// ---------------------------------------------------------------------------
__global__ __launch_bounds__(256) void finalize_kernel(
    const float* __restrict__ partials, float* __restrict__ out) {
    float acc = 0.f;
    for (int t = threadIdx.x; t < 4096; t += 256) acc += partials[t];
    #pragma unroll
    for (int off = 32; off > 0; off >>= 1) acc += __shfl_down(acc, off);
    __shared__ float sred[4];
    int lane = threadIdx.x & 63, w = threadIdx.x >> 6;
    if (lane == 0) sred[w] = acc;
    __syncthreads();
    if (threadIdx.x == 0) {
        float total = sred[0] + sred[1] + sred[2] + sred[3];
        out[0] = total * (1.0f / (8192.0f * 8192.0f));  // exact pow2 scale
    }
}

extern "C" void kernel_launch(void* const* d_in, const int* in_sizes, int n_in,
                              void* d_out, int out_size, void* d_ws, size_t ws_size,
                              hipStream_t stream) {
    const float* im = (const float*)d_in[0];
    const float* s  = (const float*)d_in[1];
    const float* ex = (const float*)d_in[2];

    // workspace layout (~16.9 MB)
    char* ws = (char*)d_ws;
    ushort* Abf   = (ushort*)(ws);                       // 8 MB
    ushort* Bbf   = (ushort*)(ws + 8388608);             // 8 MB
    float2* idat  = (float2*)(ws + 16777216);            // 64 KB
    float*  exsq  = (float*)(ws + 16842752);             // 32 KB
    float*  parts = (float*)(ws + 16875520);             // 16 KB

    prep_kernel<<<2 * NROW, 256, 0, stream>>>(im, s, ex, Abf, Bbf, idat, exsq);
    gemm_cost_kernel<<<(NROW / 128) * (NROW / 128), 256, 0, stream>>>(Abf, Bbf, idat, exsq, parts);
    finalize_kernel<<<1, 256, 0, stream>>>(parts, (float*)d_out);
}